// Round 3
// baseline (68.475 us; speedup 1.0000x reference)
//
#include <hip/hip_runtime.h>

// Problem constants (from setup_inputs): B=4, N=8192, M=8192, D=3, fp32.
constexpr int B = 4;
constexpr int N = 8192;
constexpr int M = 8192;

constexpr int QB     = 64;          // queries per block (shared by ALL waves)
constexpr int WAVES  = 4;           // waves per block (256 threads)
constexpr int QTILES = N / QB;      // 128 -> grid = B*128 = 512 = 2 blocks/CU
constexpr int MPW    = M / WAVES;   // 2048 points per wave
constexpr int TILES  = MPW / 32;    // 64 A-tiles per wave

typedef __bf16 bf16x8 __attribute__((ext_vector_type(8)));
typedef float  f32x16 __attribute__((ext_vector_type(16)));

union FragU { uint4 u; bf16x8 b; };

// fp32 -> bf16 bits, round-to-nearest-even (finite inputs only).
__device__ __host__ inline unsigned f2bf(float x) {
    unsigned u = __float_as_uint(x);
    return (u + 0x7FFFu + ((u >> 16) & 1u)) >> 16;
}
__device__ inline float bf2f(unsigned b) { return __uint_as_float(b << 16); }
__device__ inline unsigned pk(unsigned lo, unsigned hi) { return lo | (hi << 16); }

// ---------------------------------------------------------------------------
// Round-3 experiment: ELIMINATE THE ATOMIC PROTOCOL.
// Evidence: R0->R2 rewrote the main inner loop twice for ~1 us total delta,
// so the ~25 us of non-fill time is NOT loop compute (floor ~3 us). Untested
// suspect: 512K device-scope atomicMin (16-way same-address contention,
// cross-XCD coherence) + 512 KB out-init in prep + sentinel protocol.
// New shape: block owns 64 queries for ALL waves; waves split M 4-ways;
// LDS cross-wave reduce; ONE direct store per query. prep writes only wtab.
// (R1 lesson: ws poison fill (~40 us) is unconditional -> wtab in d_ws is
// free. Keep two-kernel design.)
//
// K-slot packing (mfma_f32_32x32x16_bf16, A rows = points, B cols = queries):
//   k0..3 : A=(ph0,ph0,pl0,pl0)  B=(ah0,al0,ah0,al0)  -> (ph0+pl0)(ah0+al0)
//   k4..7 : dim 1   k8..11: dim 2   k12,13: A=(sh,sl) B=(1,1) -> ||p||^2
//   k14,15: 0         (p' = -2p, everything split bf16 hi/lo)
// acc[row=point][col=query] = -2 a.p + ||p||^2   (absmax 7.8e-3, verified).
// ---------------------------------------------------------------------------

// Prep: pack each point's two A-fragment halves into wtab (32 B/point, 1 MB).
__global__ __launch_bounds__(256) void prep_kernel(const float* __restrict__ point,
                                                   uint4* __restrict__ wtab) {
    int i = blockIdx.x * 256 + threadIdx.x;   // 0 .. B*M-1
    if (i >= B * M) return;
    const float p0 = point[3 * i + 0];
    const float p1 = point[3 * i + 1];
    const float p2 = point[3 * i + 2];
    const float v0 = -2.0f * p0, v1 = -2.0f * p1, v2 = -2.0f * p2;
    const unsigned h0 = f2bf(v0), l0 = f2bf(v0 - bf2f(h0));
    const unsigned h1 = f2bf(v1), l1 = f2bf(v1 - bf2f(h1));
    const unsigned h2 = f2bf(v2), l2 = f2bf(v2 - bf2f(h2));
    const float s = fmaf(p0, p0, fmaf(p1, p1, p2 * p2));
    const unsigned sh = f2bf(s), sl = f2bf(s - bf2f(sh));
    uint4 f0, f1;
    f0.x = pk(h0, h0); f0.y = pk(l0, l0); f0.z = pk(h1, h1); f0.w = pk(l1, l1); // k0..7
    f1.x = pk(h2, h2); f1.y = pk(l2, l2); f1.z = pk(sh, sl); f1.w = 0;          // k8..15
    wtab[2 * i + 0] = f0;
    wtab[2 * i + 1] = f1;
}

// Build the B fragment for query index q (this lane's column).
__device__ inline FragU make_bfrag(const float* __restrict__ input,
                                   int b, int q, int h, float& sq_a) {
    const float* a = input + ((size_t)b * N + q) * 3;
    const float a0 = a[0], a1 = a[1], a2 = a[2];
    sq_a = fmaf(a0, a0, fmaf(a1, a1, a2 * a2));
    const unsigned ah0 = f2bf(a0), al0 = f2bf(a0 - bf2f(ah0));
    const unsigned ah1 = f2bf(a1), al1 = f2bf(a1 - bf2f(ah1));
    const unsigned ah2 = f2bf(a2), al2 = f2bf(a2 - bf2f(ah2));
    FragU bq;
    const unsigned dA = h ? pk(ah2, al2) : pk(ah0, al0);
    const unsigned dB = h ? 0x3F803F80u  : pk(ah1, al1);   // (1,1) bf16 | dim1
    bq.u.x = dA;
    bq.u.y = dA;
    bq.u.z = dB;
    bq.u.w = h ? 0u : dB;
    return bq;
}

// Main: block = 64 queries (2 B-frags, SAME for all 4 waves); wave w covers
// points [w*2048, (w+1)*2048). Per tile: 1 A-load (16B/lane), 2 mfmas,
// 16 v_min3 (8/mfma, optimal). unroll 4 -> 4 loads / 8 mfmas in flight to
// cover L2 latency at 2 waves/SIMD. Epilogue: in-lane fold + cross-half
// shuffle + LDS cross-wave reduce + ONE direct store per query. No atomics.
__global__ __launch_bounds__(256, 2) void main_kernel(const float* __restrict__ input,
                                                      const uint4* __restrict__ wtab,
                                                      float* __restrict__ out) {
    const int bid   = blockIdx.x;
    const int qtile = bid % QTILES;
    const int b     = bid / QTILES;
    const int tid   = threadIdx.x;
    const int wave  = tid >> 6;
    const int lane  = tid & 63;
    const int col   = lane & 31;          // A: point row in tile; B: query col
    const int h     = lane >> 5;          // k-half

    const int q0 = qtile * QB + col;      // same queries for every wave
    const int q1 = q0 + 32;
    float sq_a0, sq_a1;
    const FragU b0 = make_bfrag(input, b, q0, h, sq_a0);
    const FragU b1 = make_bfrag(input, b, q1, h, sq_a1);

    const uint4* __restrict__ wp =
        wtab + ((size_t)b * M + (size_t)wave * MPW) * 2;

    f32x16 cz;
    float r0[8], r1[8];
#pragma unroll
    for (int i = 0; i < 16; ++i) cz[i] = 0.0f;
#pragma unroll
    for (int i = 0; i < 8; ++i) { r0[i] = 1e30f; r1[i] = 1e30f; }

#pragma unroll 4
    for (int t = 0; t < TILES; ++t) {
        FragU fa;
        fa.u = wp[((t * 32 + col) << 1) + h];
        f32x16 acc0 = __builtin_amdgcn_mfma_f32_32x32x16_bf16(fa.b, b0.b, cz, 0, 0, 0);
        f32x16 acc1 = __builtin_amdgcn_mfma_f32_32x32x16_bf16(fa.b, b1.b, cz, 0, 0, 0);
#pragma unroll
        for (int j = 0; j < 8; ++j)
            r0[j] = fminf(fminf(r0[j], acc0[2 * j]), acc0[2 * j + 1]);   // v_min3
#pragma unroll
        for (int j = 0; j < 8; ++j)
            r1[j] = fminf(fminf(r1[j], acc1[2 * j]), acc1[2 * j + 1]);   // v_min3
    }

    // In-lane fold 8 -> 1 (v_min3 tree), then cross-half shuffle.
    float m0 = fminf(fminf(r0[0], r0[1]), r0[2]);
    m0 = fminf(fminf(m0, r0[3]), r0[4]);
    m0 = fminf(fminf(m0, r0[5]), r0[6]);
    m0 = fminf(m0, r0[7]);
    float m1 = fminf(fminf(r1[0], r1[1]), r1[2]);
    m1 = fminf(fminf(m1, r1[3]), r1[4]);
    m1 = fminf(fminf(m1, r1[5]), r1[6]);
    m1 = fminf(m1, r1[7]);
    m0 = fminf(m0, __shfl_xor(m0, 32, 64));
    m1 = fminf(m1, __shfl_xor(m1, 32, 64));

    // Cross-wave reduce in LDS (1 KB), then ONE coalesced store per query.
    __shared__ float red[WAVES][QB];
    if (lane < 32) {
        red[wave][col]      = m0;
        red[wave][col + 32] = m1;
    }
    __syncthreads();
    if (tid < QB) {
        // thread tid (wave 0): tid<32 -> its q0 == qbase+tid (use sq_a0),
        // tid>=32 -> its q1 == qbase+tid (use sq_a1).
        const float m = fminf(fminf(red[0][tid], red[1][tid]),
                              fminf(red[2][tid], red[3][tid]));
        const float sq = (tid < 32) ? sq_a0 : sq_a1;
        out[(size_t)b * N + (size_t)qtile * QB + tid] = fmaxf(m + sq, 0.0f);
    }
}

extern "C" void kernel_launch(void* const* d_in, const int* in_sizes, int n_in,
                              void* d_out, int out_size, void* d_ws, size_t ws_size,
                              hipStream_t stream) {
    const float* input = (const float*)d_in[0];   // [B, N, 3] fp32
    const float* point = (const float*)d_in[1];   // [B, M, 3] fp32
    float* out         = (float*)d_out;           // [B, N] fp32

    uint4* wtab = (uint4*)d_ws;                   // 1 MB packed A-fragment table

    const int prep_grid = (B * M + 255) / 256;    // 128 blocks
    const int main_grid = B * QTILES;             // 512 blocks

    prep_kernel<<<prep_grid, 256, 0, stream>>>(point, wtab);
    main_kernel<<<main_grid, 256, 0, stream>>>(input, wtab, out);
}

// Round 4
// 64.637 us; speedup vs baseline: 1.0594x; 1.0594x over previous
//
#include <hip/hip_runtime.h>

// Problem constants (from setup_inputs): B=4, N=8192, M=8192, D=3, fp32.
constexpr int B = 4;
constexpr int N = 8192;
constexpr int M = 8192;

constexpr int QPW     = 64;            // queries per wave (2 B-fragments)
constexpr int WAVES   = 4;             // waves per block
constexpr int QB      = QPW * WAVES;   // 256 queries per block
constexpr int QTILES  = N / QB;        // 32
constexpr int PCHUNKS = 8;             // R4: 16 -> 8. grid 1024 = exactly
                                       // 4 blocks/CU resident -> ONE round,
                                       // no residency tail; prologues and
                                       // atomics halve; loop 2x longer.
constexpr int CHUNK   = M / PCHUNKS;   // 1024 points per block (32 KB, L1-fit)
constexpr int PTILES  = CHUNK / 32;    // 32 A-tiles, 64 mfmas per wave

typedef __bf16 bf16x8 __attribute__((ext_vector_type(8)));
typedef float  f32x16 __attribute__((ext_vector_type(16)));

union FragU { uint4 u; bf16x8 b; };

// fp32 -> bf16 bits, round-to-nearest-even (finite inputs only).
__device__ __host__ inline unsigned f2bf(float x) {
    unsigned u = __float_as_uint(x);
    return (u + 0x7FFFu + ((u >> 16) & 1u)) >> 16;
}
__device__ inline float bf2f(unsigned b) { return __uint_as_float(b << 16); }
__device__ inline unsigned pk(unsigned lo, unsigned hi) { return lo | (hi << 16); }

// ---------------------------------------------------------------------------
// Session ledger (what moved the needle and what didn't):
//  R1: fused no-ws kernel  -> +5.7 us. ws poison fill (~40 us, 84% HBM peak)
//      is UNCONDITIONAL -> wtab in d_ws is free. Two-kernel design stays.
//  R2: within-acc min3 fold + launch_bounds(256,4): 66.3 -> 65.2 us (best).
//  R3: atomic-free LDS-reduce shape -> +3.3 us. Atomics were NOT the cost;
//      occupancy (2 waves/SIMD) + L1 thrash (64 KB/wave streams) hurt more.
//  R4 (this): PCHUNKS 16->8 on the R2 winner. One residency round
//      (1024 blocks = 4/CU), half the wave-prologues, half the atomics,
//      2x loop length amortizes the B-frag build.
//
// K-slot packing (mfma_f32_32x32x16_bf16, A rows = points, B cols = queries):
//   k0..3 : A=(ph0,ph0,pl0,pl0)  B=(ah0,al0,ah0,al0)  -> (ph0+pl0)(ah0+al0)
//   k4..7 : dim 1   k8..11: dim 2   k12,13: A=(sh,sl) B=(1,1) -> ||p||^2
//   k14,15: 0         (p' = -2p, everything split bf16 hi/lo)
// acc[row=point][col=query] = -2 a.p + ||p||^2   (absmax 7.8e-3, verified).
// ---------------------------------------------------------------------------

// Prep: pack each point's two A-fragment halves into wtab (32 B/point, 1 MB)
// AND initialize out to 0x7F7F7F7F (uint order == float order for
// non-negative floats, so atomicMin(uint) implements float min). B*M == B*N.
__global__ __launch_bounds__(256) void prep_kernel(const float* __restrict__ point,
                                                   uint4* __restrict__ wtab,
                                                   unsigned int* __restrict__ out) {
    int i = blockIdx.x * 256 + threadIdx.x;   // 0 .. B*M-1
    if (i >= B * M) return;
    const float p0 = point[3 * i + 0];
    const float p1 = point[3 * i + 1];
    const float p2 = point[3 * i + 2];
    const float v0 = -2.0f * p0, v1 = -2.0f * p1, v2 = -2.0f * p2;
    const unsigned h0 = f2bf(v0), l0 = f2bf(v0 - bf2f(h0));
    const unsigned h1 = f2bf(v1), l1 = f2bf(v1 - bf2f(h1));
    const unsigned h2 = f2bf(v2), l2 = f2bf(v2 - bf2f(h2));
    const float s = fmaf(p0, p0, fmaf(p1, p1, p2 * p2));
    const unsigned sh = f2bf(s), sl = f2bf(s - bf2f(sh));
    uint4 f0, f1;
    f0.x = pk(h0, h0); f0.y = pk(l0, l0); f0.z = pk(h1, h1); f0.w = pk(l1, l1); // k0..7
    f1.x = pk(h2, h2); f1.y = pk(l2, l2); f1.z = pk(sh, sl); f1.w = 0;          // k8..15
    wtab[2 * i + 0] = f0;
    wtab[2 * i + 1] = f1;
    out[i] = 0x7F7F7F7Fu;
}

// Build the B fragment for query index q (this lane's column).
__device__ inline FragU make_bfrag(const float* __restrict__ input,
                                   int b, int q, int h, float& sq_a) {
    const float* a = input + ((size_t)b * N + q) * 3;
    const float a0 = a[0], a1 = a[1], a2 = a[2];
    sq_a = fmaf(a0, a0, fmaf(a1, a1, a2 * a2));
    const unsigned ah0 = f2bf(a0), al0 = f2bf(a0 - bf2f(ah0));
    const unsigned ah1 = f2bf(a1), al1 = f2bf(a1 - bf2f(ah1));
    const unsigned ah2 = f2bf(a2), al2 = f2bf(a2 - bf2f(ah2));
    FragU bq;
    const unsigned dA = h ? pk(ah2, al2) : pk(ah0, al0);
    const unsigned dB = h ? 0x3F803F80u  : pk(ah1, al1);   // (1,1) bf16 | dim1
    bq.u.x = dA;
    bq.u.y = dA;
    bq.u.z = dB;
    bq.u.w = h ? 0u : dB;
    return bq;
}

// Main: one wave = 64 queries (2 B frags) vs its 1024-point chunk.
// Per tile pair: 2 A-loads (16B/lane, L1-resident after first wave),
// 4 mfmas, 64 v_min3 (8/mfma, optimal); within-acc folding keeps only
// 1-2 accs live. unroll 2 -> 4 loads in flight.
__global__ __launch_bounds__(256, 4) void main_kernel(const float* __restrict__ input,
                                                      const uint4* __restrict__ wtab,
                                                      unsigned int* __restrict__ out) {
    const int bid    = blockIdx.x;
    const int pchunk = bid % PCHUNKS;
    const int qtile  = (bid / PCHUNKS) % QTILES;
    const int b      = bid / (PCHUNKS * QTILES);
    const int tid    = threadIdx.x;
    const int wave   = tid >> 6;
    const int lane   = tid & 63;
    const int col    = lane & 31;          // A: point row in tile; B: query col
    const int h      = lane >> 5;          // k-half

    const int q0 = qtile * QB + wave * QPW + col;        // first query set
    const int q1 = q0 + 32;                              // second query set
    float sq_a0, sq_a1;
    const FragU b0 = make_bfrag(input, b, q0, h, sq_a0);
    const FragU b1 = make_bfrag(input, b, q1, h, sq_a1);

    const uint4* __restrict__ wp =
        wtab + ((size_t)b * M + (size_t)pchunk * CHUNK) * 2;

    f32x16 cz;
    float r0[8], r1[8];
#pragma unroll
    for (int i = 0; i < 16; ++i) cz[i] = 0.0f;
#pragma unroll
    for (int i = 0; i < 8; ++i) { r0[i] = 1e30f; r1[i] = 1e30f; }

#pragma unroll 2
    for (int t = 0; t < PTILES; t += 2) {
        FragU fa0, fa1;
        fa0.u = wp[((t * 32 + col) << 1) + h];
        fa1.u = wp[(((t + 1) * 32 + col) << 1) + h];
        // Fold each acc within itself: r[j] = min3(r[j], acc[2j], acc[2j+1]),
        // 8 v_min3 per mfma (optimal), each fold depends on ONE mfma.
        {
            f32x16 accA = __builtin_amdgcn_mfma_f32_32x32x16_bf16(fa0.b, b0.b, cz, 0, 0, 0);
            f32x16 accB = __builtin_amdgcn_mfma_f32_32x32x16_bf16(fa1.b, b0.b, cz, 0, 0, 0);
#pragma unroll
            for (int j = 0; j < 8; ++j)
                r0[j] = fminf(fminf(r0[j], accA[2 * j]), accA[2 * j + 1]);
#pragma unroll
            for (int j = 0; j < 8; ++j)
                r0[j] = fminf(fminf(r0[j], accB[2 * j]), accB[2 * j + 1]);
        }
        {
            f32x16 accA = __builtin_amdgcn_mfma_f32_32x32x16_bf16(fa0.b, b1.b, cz, 0, 0, 0);
            f32x16 accB = __builtin_amdgcn_mfma_f32_32x32x16_bf16(fa1.b, b1.b, cz, 0, 0, 0);
#pragma unroll
            for (int j = 0; j < 8; ++j)
                r1[j] = fminf(fminf(r1[j], accA[2 * j]), accA[2 * j + 1]);
#pragma unroll
            for (int j = 0; j < 8; ++j)
                r1[j] = fminf(fminf(r1[j], accB[2 * j]), accB[2 * j + 1]);
        }
    }

    // Epilogue: fold 8 -> 1 in-lane (v_min3 tree), then cross-half shuffle.
    float m0 = fminf(fminf(r0[0], r0[1]), r0[2]);
    m0 = fminf(fminf(m0, r0[3]), r0[4]);
    m0 = fminf(fminf(m0, r0[5]), r0[6]);
    m0 = fminf(m0, r0[7]);
    float m1 = fminf(fminf(r1[0], r1[1]), r1[2]);
    m1 = fminf(fminf(m1, r1[3]), r1[4]);
    m1 = fminf(fminf(m1, r1[5]), r1[6]);
    m1 = fminf(m1, r1[7]);
    m0 = fminf(m0, __shfl_xor(m0, 32, 64));
    m1 = fminf(m1, __shfl_xor(m1, 32, 64));

    if (lane < 32) {
        atomicMin(&out[(size_t)b * N + q0], __float_as_uint(fmaxf(m0 + sq_a0, 0.0f)));
        atomicMin(&out[(size_t)b * N + q1], __float_as_uint(fmaxf(m1 + sq_a1, 0.0f)));
    }
}

extern "C" void kernel_launch(void* const* d_in, const int* in_sizes, int n_in,
                              void* d_out, int out_size, void* d_ws, size_t ws_size,
                              hipStream_t stream) {
    const float* input = (const float*)d_in[0];   // [B, N, 3] fp32
    const float* point = (const float*)d_in[1];   // [B, M, 3] fp32
    unsigned int* out  = (unsigned int*)d_out;    // [B, N] fp32 viewed as uint

    uint4* wtab = (uint4*)d_ws;                   // 1 MB packed A-fragment table

    const int prep_grid = (B * M + 255) / 256;        // 128 blocks
    const int main_grid = B * QTILES * PCHUNKS;       // 1024 blocks, 4/CU

    prep_kernel<<<prep_grid, 256, 0, stream>>>(point, wtab, out);
    main_kernel<<<main_grid, 256, 0, stream>>>(input, wtab, out);
}